// Round 2
// baseline (347.112 us; speedup 1.0000x reference)
//
#include <hip/hip_runtime.h>

// B=8, HEADS=8, N=3136, D=32, K2=9 — all fp32.
constexpr int Bc   = 8;
constexpr int Hh   = 8;
constexpr int Nn   = 3136;
constexpr int Dd   = 32;
constexpr int K2c  = 9;
constexpr int ROWS = Bc * Hh * Nn;            // 200704 flattened (b,h,n) rows
constexpr int RPB  = 8;                       // rows per block (N%8==0 -> h uniform)
constexpr int BLOCK = 256;
constexpr int VT4  = RPB * Dd * K2c / 4;      // 576 float4s in the v tile

__global__ __launch_bounds__(BLOCK, 4)
void swattn_av_kernel(const float* __restrict__ q,          // [B,H,N,D]
                      const float* __restrict__ attn_local, // [B,H,N,K2]
                      const float* __restrict__ v,          // [B,H,N,D,K2]
                      const float* __restrict__ tok,        // [H,D,K2]
                      const float* __restrict__ bias,       // [H,N,K2]
                      float* __restrict__ out) {            // [B,H,N,D]
    __shared__ float4 v_lds4[VT4];                   // 9216 B: 8 rows x 288 floats
    __shared__ float  T_lds[Dd * K2c] __attribute__((aligned(16)));  // 288
    __shared__ float  q_lds[RPB][Dd + 1];            // pad -> conflict-free col reads
    __shared__ float  attn_lds[RPB][K2c];            // 8 x 9 shared attn weights

    const int tid  = threadIdx.x;
    const int base = blockIdx.x * RPB;               // first global row of this block
    const int h    = (base / Nn) % Hh;               // uniform across the block

    // ---- Stage v tile: 576 coalesced float4 loads (global_load_dwordx4) ----
    {
        const float4* __restrict__ vsrc = (const float4*)(v + (size_t)base * (Dd * K2c));
        v_lds4[tid]       = vsrc[tid];
        v_lds4[tid + 256] = vsrc[tid + 256];
        if (tid < VT4 - 512) v_lds4[tid + 512] = vsrc[tid + 512];
    }
    // ---- Stage q rows: 64 float4 loads ----
    if (tid < RPB * Dd / 4) {
        const int lrow = tid >> 3, dg = tid & 7;
        const float4 qv = ((const float4*)(q + (size_t)(base + lrow) * Dd))[dg];
        q_lds[lrow][dg * 4 + 0] = qv.x;
        q_lds[lrow][dg * 4 + 1] = qv.y;
        q_lds[lrow][dg * 4 + 2] = qv.z;
        q_lds[lrow][dg * 4 + 3] = qv.w;
    }
    // ---- Stage learnable_tokens: 72 float4 loads ----
    if (tid < Dd * K2c / 4)
        ((float4*)T_lds)[tid] = ((const float4*)(tok + (size_t)h * Dd * K2c))[tid];

    // ---- Prefetch attn_local + bias for Phase A (contiguous 72 floats each) ----
    float al = 0.f, bi = 0.f;
    if (tid < RPB * K2c) {
        al = attn_local[(size_t)base * K2c + tid];
        bi = bias[(size_t)(base % (Hh * Nn)) * K2c + tid];
    }
    __syncthreads();

    // ---- Phase A: 72 threads -> attn[lrow][k] = q . T[:,k] + bias + local ----
    if (tid < RPB * K2c) {
        const int lrow = tid / K2c;
        const int k    = tid - lrow * K2c;
        float s0 = 0.f, s1 = 0.f, s2 = 0.f, s3 = 0.f;
        #pragma unroll
        for (int d = 0; d < Dd; d += 4) {
            s0 += q_lds[lrow][d + 0] * T_lds[(d + 0) * K2c + k];
            s1 += q_lds[lrow][d + 1] * T_lds[(d + 1) * K2c + k];
            s2 += q_lds[lrow][d + 2] * T_lds[(d + 2) * K2c + k];
            s3 += q_lds[lrow][d + 3] * T_lds[(d + 3) * K2c + k];
        }
        attn_lds[lrow][k] = ((s0 + s1) + (s2 + s3)) + al + bi;
    }
    __syncthreads();

    // ---- Phase B: 256 threads, one output each, v from LDS ----
    {
        const int lrow = tid >> 5, d = tid & 31;
        const float* __restrict__ vr =
            (const float*)v_lds4 + lrow * (Dd * K2c) + d * K2c;
        float acc = 0.f;
        #pragma unroll
        for (int k = 0; k < K2c; ++k)
            acc += attn_lds[lrow][k] * vr[k];
        out[(size_t)base * Dd + tid] = acc;   // contiguous 256 floats, coalesced
    }
}

extern "C" void kernel_launch(void* const* d_in, const int* in_sizes, int n_in,
                              void* d_out, int out_size, void* d_ws, size_t ws_size,
                              hipStream_t stream) {
    const float* q          = (const float*)d_in[0];   // q_norm          [B,H,N,D]
    const float* attn_local = (const float*)d_in[1];   // attn_local      [B,H,N,K2]
    const float* v          = (const float*)d_in[2];   // v_local         [B,H,N,D,K2]
    const float* tok        = (const float*)d_in[3];   // learnable_tokens[H,D,K2]
    const float* bias       = (const float*)d_in[4];   // learnable_bias  [H,N,K2]
    float* out = (float*)d_out;

    const int grid = ROWS / RPB;                       // 25088, exact
    swattn_av_kernel<<<grid, BLOCK, 0, stream>>>(q, attn_local, v, tok, bias, out);
}